// Round 1
// baseline (883.826 us; speedup 1.0000x reference)
//
#include <hip/hip_runtime.h>

typedef short bf16x8 __attribute__((ext_vector_type(8)));
typedef float f32x4 __attribute__((ext_vector_type(4)));
typedef float f32x2 __attribute__((ext_vector_type(2)));
typedef unsigned short u16;
typedef u16 u16x4 __attribute__((ext_vector_type(4)));

#define L_SEQ 1024
#define IDIM_ 2048
#define H_ 16
#define DK_ 128
#define DV_ 128
#define KEYD 2048
#define VALD 2048
#define CONVD 6144

__device__ __forceinline__ u16 f2bf(float f) {
  union { float f; unsigned u; } v; v.f = f;
  unsigned r = v.u + 0x7FFF + ((v.u >> 16) & 1);  // RNE
  return (u16)(r >> 16);
}

// ---------------- cast x (f32 -> bf16), vectorized x4 ----------------
__global__ __launch_bounds__(256) void castx_kernel(const float* __restrict__ x,
                                                    u16* __restrict__ xb) {
  int i = (blockIdx.x * 256 + threadIdx.x) * 4;
  f32x4 v = *(const f32x4*)&x[i];
  u16x4 o = { f2bf(v[0]), f2bf(v[1]), f2bf(v[2]), f2bf(v[3]) };
  *(u16x4*)&xb[i] = o;
}

// ------------- transpose + cast: W[R][C] f32 -> WT[C][R] bf16 -------------
__global__ __launch_bounds__(256) void tcast_kernel(const float* __restrict__ W,
                                                    u16* __restrict__ WT,
                                                    int R, int C) {
  __shared__ float tile[32][33];
  int c0 = blockIdx.x * 32, r0 = blockIdx.y * 32;
  int tx = threadIdx.x & 31, ty = threadIdx.x >> 5;  // 32 x 8
#pragma unroll
  for (int j = 0; j < 4; ++j)
    tile[ty + j * 8][tx] = W[(size_t)(r0 + ty + j * 8) * C + c0 + tx];
  __syncthreads();
#pragma unroll
  for (int j = 0; j < 4; ++j)
    WT[(size_t)(c0 + ty + j * 8) * R + r0 + tx] = f2bf(tile[tx][ty + j * 8]);
}

// ---------------- NT GEMM: A[M,K] bf16, B[N,K] bf16 -> C[M,N] f32 ----------------
// 128x128 tile, BK=64, 4 waves (2x2 of 64x64), mfma_f32_16x16x32_bf16.
__global__ __launch_bounds__(256) void gemm_bt_kernel(const u16* __restrict__ A,
                                                      const u16* __restrict__ B,
                                                      float* __restrict__ C,
                                                      int M, int N, int K) {
  __shared__ short As[128 * 72];  // pad 64 -> 72 (bank-conflict relief)
  __shared__ short Bs[128 * 72];
  const int tid = threadIdx.x;
  const int lane = tid & 63, wave = tid >> 6;
  const int wm = wave >> 1, wn = wave & 1;
  const int m0 = blockIdx.y * 128, n0 = blockIdx.x * 128;
  const int l15 = lane & 15, lhi = lane >> 4;

  f32x4 acc[4][4] = {};

  for (int k0 = 0; k0 < K; k0 += 64) {
    __syncthreads();
#pragma unroll
    for (int i = 0; i < 4; ++i) {
      int chunk = tid + i * 256;          // 0..1023
      int row = chunk >> 3;               // 128 rows
      int kc = (chunk & 7) * 8;           // 8 chunks of 8 bf16 per row
      *(bf16x8*)&As[row * 72 + kc] =
          *(const bf16x8*)&A[(size_t)(m0 + row) * K + k0 + kc];
      *(bf16x8*)&Bs[row * 72 + kc] =
          *(const bf16x8*)&B[(size_t)(n0 + row) * K + k0 + kc];
    }
    __syncthreads();
#pragma unroll
    for (int kk = 0; kk < 64; kk += 32) {
      const int koff = kk + lhi * 8;
      bf16x8 a[4], b[4];
#pragma unroll
      for (int m = 0; m < 4; ++m)
        a[m] = *(const bf16x8*)&As[(wm * 64 + m * 16 + l15) * 72 + koff];
#pragma unroll
      for (int n = 0; n < 4; ++n)
        b[n] = *(const bf16x8*)&Bs[(wn * 64 + n * 16 + l15) * 72 + koff];
#pragma unroll
      for (int m = 0; m < 4; ++m)
#pragma unroll
        for (int n = 0; n < 4; ++n)
          acc[m][n] = __builtin_amdgcn_mfma_f32_16x16x32_bf16(a[m], b[n], acc[m][n], 0, 0, 0);
    }
  }
#pragma unroll
  for (int m = 0; m < 4; ++m)
#pragma unroll
    for (int n = 0; n < 4; ++n)
#pragma unroll
      for (int j = 0; j < 4; ++j) {
        int row = m0 + wm * 64 + m * 16 + lhi * 4 + j;
        int col = n0 + wn * 64 + n * 16 + l15;
        C[(size_t)row * N + col] = acc[m][n][j];
      }
}

// ---------------- causal depthwise conv (K=4) + SiLU ----------------
__global__ __launch_bounds__(256) void conv_silu_kernel(const float* __restrict__ qkv,
                                                        const float* __restrict__ cw,
                                                        float* __restrict__ qkvc) {
  int idx = blockIdx.x * 256 + threadIdx.x;  // over L*CONVD
  int l = idx / CONVD, c = idx - l * CONVD;
  f32x4 w = *(const f32x4*)&cw[c * 4];
  float s = qkv[idx] * w[3];
  if (l >= 1) s += qkv[idx - CONVD] * w[2];
  if (l >= 2) s += qkv[idx - 2 * CONVD] * w[1];
  if (l >= 3) s += qkv[idx - 3 * CONVD] * w[0];
  qkvc[idx] = s / (1.f + expf(-s));  // silu
}

// ---------------- beta = sigmoid(xWb), eg = exp(softplus(xWa+bias)*(-exp(A_log))) ----------------
__global__ __launch_bounds__(128) void betag_kernel(const float* __restrict__ x,
                                                    const float* __restrict__ Wb,
                                                    const float* __restrict__ Wa,
                                                    const float* __restrict__ A_log,
                                                    const float* __restrict__ dt_bias,
                                                    float* __restrict__ beta,
                                                    float* __restrict__ eg) {
  int l = blockIdx.x;
  __shared__ float xs[IDIM_];
  __shared__ float redb[128], reda[128];
  for (int i = threadIdx.x; i < IDIM_; i += 128) xs[i] = x[(size_t)l * IDIM_ + i];
  __syncthreads();
  int h = threadIdx.x & 15, part = threadIdx.x >> 4;  // 16 h x 8 parts
  float sb = 0.f, sa = 0.f;
  int d0 = part * 256;
  for (int d = d0; d < d0 + 256; ++d) {
    float xv = xs[d];
    sb += xv * Wb[d * 16 + h];
    sa += xv * Wa[d * 16 + h];
  }
  redb[threadIdx.x] = sb;
  reda[threadIdx.x] = sa;
  __syncthreads();
  if (threadIdx.x < 16) {
    float b = 0.f, a = 0.f;
#pragma unroll
    for (int p = 0; p < 8; ++p) { b += redb[p * 16 + h]; a += reda[p * 16 + h]; }
    beta[l * 16 + h] = 1.f / (1.f + expf(-b));
    float dtv = a + dt_bias[h];
    dtv = (dtv > 20.f) ? dtv : log1pf(expf(dtv));  // softplus
    float g = -expf(A_log[h]) * dtv;
    eg[l * 16 + h] = expf(g);
  }
}

// ---------------- l2norm q (with scale) and k, in place ----------------
__global__ __launch_bounds__(256) void l2norm_kernel(float* __restrict__ qkvc) {
  int wid = blockIdx.x * 4 + (threadIdx.x >> 6);  // 32768 waves: (l,h,which)
  int lane = threadIdx.x & 63;
  int which = wid & 1;
  int lh = wid >> 1;
  int l = lh >> 4, h = lh & 15;
  float* base = qkvc + (size_t)l * CONVD + which * KEYD + h * 128;
  f32x2 v = *(f32x2*)&base[lane * 2];
  float ss = v[0] * v[0] + v[1] * v[1];
#pragma unroll
  for (int s = 1; s < 64; s <<= 1) ss += __shfl_xor(ss, s);
  float sc = 1.f / sqrtf(ss + 1e-6f);
  if (which == 0) sc *= 0.08838834764831845f;  // DK^-0.5
  v[0] *= sc; v[1] *= sc;
  *(f32x2*)&base[lane * 2] = v;
}

// ---------------- sequential delta-rule scan ----------------
// 2048 columns (h,dv); 16 lanes per column, 8 dk-state regs per lane.
__global__ __launch_bounds__(256) void scan_kernel(const float* __restrict__ qkvc,
                                                   const float* __restrict__ eg,
                                                   const float* __restrict__ beta,
                                                   float* __restrict__ oatt) {
  const int tid = threadIdx.x;
  const int dk_sub = tid & 15;
  const int col = blockIdx.x * 16 + (tid >> 4);  // 0..2047
  const int h = col >> 7, dv = col & 127;
  const int dkb = dk_sub * 8;
  const float* qp = qkvc + h * 128 + dkb;
  const float* kp = qkvc + KEYD + h * 128 + dkb;
  const float* vp = qkvc + 2 * KEYD + h * 128 + dv;

  float M[8] = {0.f, 0.f, 0.f, 0.f, 0.f, 0.f, 0.f, 0.f};
  f32x4 kc0 = *(const f32x4*)&kp[0], kc1 = *(const f32x4*)&kp[4];
  f32x4 qc0 = *(const f32x4*)&qp[0], qc1 = *(const f32x4*)&qp[4];
  float vc = *vp, ec = eg[h], bc = beta[h];

#pragma unroll 1
  for (int l = 0; l < L_SEQ; ++l) {
    f32x4 kn0 = {}, kn1 = {}, qn0 = {}, qn1 = {};
    float vn = 0.f, en = 0.f, bn = 0.f;
    if (l + 1 < L_SEQ) {  // prefetch next step
      size_t roff = (size_t)(l + 1) * CONVD;
      kn0 = *(const f32x4*)&kp[roff]; kn1 = *(const f32x4*)&kp[roff + 4];
      qn0 = *(const f32x4*)&qp[roff]; qn1 = *(const f32x4*)&qp[roff + 4];
      vn = vp[roff];
      en = eg[(l + 1) * 16 + h]; bn = beta[(l + 1) * 16 + h];
    }
    float mk = 0.f, qm = 0.f, qk = 0.f;
#pragma unroll
    for (int i = 0; i < 8; ++i) {
      float kv = (i < 4) ? kc0[i] : kc1[i - 4];
      float qv = (i < 4) ? qc0[i] : qc1[i - 4];
      float m = ec * M[i];
      M[i] = m;
      mk += kv * m;
      qm += qv * m;
      qk += qv * kv;
    }
#pragma unroll
    for (int s = 1; s < 16; s <<= 1) {  // butterfly over the 16 dk lanes
      mk += __shfl_xor(mk, s);
      qm += __shfl_xor(qm, s);
      qk += __shfl_xor(qk, s);
    }
    float delta = (vc - mk) * bc;
    if (dk_sub == 0) oatt[(size_t)(l * 16 + h) * 128 + dv] = qm + qk * delta;
#pragma unroll
    for (int i = 0; i < 8; ++i) {
      float kv = (i < 4) ? kc0[i] : kc1[i - 4];
      M[i] += kv * delta;
    }
    kc0 = kn0; kc1 = kn1; qc0 = qn0; qc1 = qn1; vc = vn; ec = en; bc = bn;
  }
}

// ---------------- gated RMSNorm -> bf16 ----------------
__global__ __launch_bounds__(256) void grms_kernel(const float* __restrict__ oatt,
                                                   const float* __restrict__ z,
                                                   const float* __restrict__ norm_w,
                                                   u16* __restrict__ gn) {
  int wid = blockIdx.x * 4 + (threadIdx.x >> 6);  // 16384 waves: l*16+h
  int lane = threadIdx.x & 63;
  int l = wid >> 4, h = wid & 15;
  const float* o = oatt + (size_t)wid * 128;
  f32x2 ov = *(const f32x2*)&o[lane * 2];
  float ss = ov[0] * ov[0] + ov[1] * ov[1];
#pragma unroll
  for (int s = 1; s < 64; s <<= 1) ss += __shfl_xor(ss, s);
  float r = 1.f / sqrtf(ss * (1.f / 128.f) + 1e-6f);
  const float* zp = z + (size_t)l * VALD + h * 128;
  f32x2 zv = *(const f32x2*)&zp[lane * 2];
  u16 r0, r1;
  {
    float sil = zv[0] / (1.f + expf(-zv[0]));
    r0 = f2bf(ov[0] * r * norm_w[lane * 2] * sil);
    float sil1 = zv[1] / (1.f + expf(-zv[1]));
    r1 = f2bf(ov[1] * r * norm_w[lane * 2 + 1] * sil1);
  }
  u16* dst = gn + (size_t)l * VALD + h * 128 + lane * 2;
  dst[0] = r0; dst[1] = r1;
}

extern "C" void kernel_launch(void* const* d_in, const int* in_sizes, int n_in,
                              void* d_out, int out_size, void* d_ws, size_t ws_size,
                              hipStream_t stream) {
  const float* x      = (const float*)d_in[0];
  const float* Wqkv   = (const float*)d_in[1];
  const float* Wz     = (const float*)d_in[2];
  const float* Wb     = (const float*)d_in[3];
  const float* Wa     = (const float*)d_in[4];
  const float* conv_w = (const float*)d_in[5];
  const float* A_log  = (const float*)d_in[6];
  const float* dt_bias= (const float*)d_in[7];
  const float* norm_w = (const float*)d_in[8];
  const float* Wout   = (const float*)d_in[9];
  float* out = (float*)d_out;

  char* ws = (char*)d_ws;
  size_t off = 0;
  auto alloc = [&](size_t bytes) {
    void* p = ws + off;
    off = (off + bytes + 255) & ~(size_t)255;
    return p;
  };
  u16* xb     = (u16*)alloc((size_t)L_SEQ * IDIM_ * 2);
  u16* WqkvT  = (u16*)alloc((size_t)CONVD * IDIM_ * 2);
  u16* WzT    = (u16*)alloc((size_t)VALD * IDIM_ * 2);
  u16* WoutT  = (u16*)alloc((size_t)IDIM_ * VALD * 2);
  float* qkv  = (float*)alloc((size_t)L_SEQ * CONVD * 4);
  float* qkvc = (float*)alloc((size_t)L_SEQ * CONVD * 4);
  float* zbuf = (float*)alloc((size_t)L_SEQ * VALD * 4);
  float* beta = (float*)alloc((size_t)L_SEQ * H_ * 4);
  float* eg   = (float*)alloc((size_t)L_SEQ * H_ * 4);
  float* oatt = (float*)alloc((size_t)L_SEQ * H_ * DV_ * 4);
  u16* gn     = (u16*)alloc((size_t)L_SEQ * VALD * 2);

  // casts / transposes
  castx_kernel<<<(L_SEQ * IDIM_) / 1024, 256, 0, stream>>>(x, xb);
  tcast_kernel<<<dim3(CONVD / 32, IDIM_ / 32), 256, 0, stream>>>(Wqkv, WqkvT, IDIM_, CONVD);
  tcast_kernel<<<dim3(VALD / 32, IDIM_ / 32), 256, 0, stream>>>(Wz, WzT, IDIM_, VALD);
  tcast_kernel<<<dim3(IDIM_ / 32, VALD / 32), 256, 0, stream>>>(Wout, WoutT, VALD, IDIM_);

  // projections
  gemm_bt_kernel<<<dim3(CONVD / 128, L_SEQ / 128), 256, 0, stream>>>(xb, WqkvT, qkv, L_SEQ, CONVD, IDIM_);
  gemm_bt_kernel<<<dim3(VALD / 128, L_SEQ / 128), 256, 0, stream>>>(xb, WzT, zbuf, L_SEQ, VALD, IDIM_);

  // conv + silu, gates, l2norm
  conv_silu_kernel<<<(L_SEQ * CONVD) / 256, 256, 0, stream>>>(qkv, conv_w, qkvc);
  betag_kernel<<<L_SEQ, 128, 0, stream>>>(x, Wb, Wa, A_log, dt_bias, beta, eg);
  l2norm_kernel<<<(L_SEQ * H_ * 2) / 4, 256, 0, stream>>>(qkvc);

  // sequential scan
  scan_kernel<<<(H_ * DV_) / 16, 256, 0, stream>>>(qkvc, eg, beta, oatt);

  // gated rmsnorm + final projection
  grms_kernel<<<(L_SEQ * H_) / 4, 256, 0, stream>>>(oatt, zbuf, norm_w, gn);
  gemm_bt_kernel<<<dim3(IDIM_ / 128, L_SEQ / 128), 256, 0, stream>>>(gn, WoutT, out, L_SEQ, IDIM_, VALD);
}

// Round 3
// 430.111 us; speedup vs baseline: 2.0549x; 2.0549x over previous
//
#include <hip/hip_runtime.h>

typedef short bf16x8 __attribute__((ext_vector_type(8)));
typedef float f32x4 __attribute__((ext_vector_type(4)));
typedef float f32x2 __attribute__((ext_vector_type(2)));
typedef unsigned short u16;
typedef u16 u16x4 __attribute__((ext_vector_type(4)));

#define L_SEQ 1024
#define IDIM_ 2048
#define H_ 16
#define DK_ 128
#define DV_ 128
#define KEYD 2048
#define VALD 2048
#define CONVD 6144
#define CH 16
#define NCH (L_SEQ / CH)

__device__ __forceinline__ u16 f2bf(float f) {
  union { float f; unsigned u; } v; v.f = f;
  unsigned r = v.u + 0x7FFF + ((v.u >> 16) & 1);  // RNE
  return (u16)(r >> 16);
}

// 16-lane allreduce, all-DPP (VALU only):
// xor1 (quad_perm[1,0,3,2]), xor2 (quad_perm[2,3,0,1]),
// row_half_mirror (==xor4 once quads uniform), row_mirror (==xor8 once octets uniform)
__device__ __forceinline__ float red16(float x) {
  union U { float f; int i; } a, t;
  a.f = x;
  t.i = __builtin_amdgcn_update_dpp(0, a.i, 0xB1, 0xF, 0xF, true); a.f += t.f;
  t.i = __builtin_amdgcn_update_dpp(0, a.i, 0x4E, 0xF, 0xF, true); a.f += t.f;
  t.i = __builtin_amdgcn_update_dpp(0, a.i, 0x141, 0xF, 0xF, true); a.f += t.f;
  t.i = __builtin_amdgcn_update_dpp(0, a.i, 0x140, 0xF, 0xF, true); a.f += t.f;
  return a.f;
}

__device__ __forceinline__ void gl_lds16(const float* g, float* l) {
  __builtin_amdgcn_global_load_lds(
      (const __attribute__((address_space(1))) void*)g,
      (__attribute__((address_space(3))) void*)l, 16, 0, 0);
}
__device__ __forceinline__ void gl_lds4(const float* g, float* l) {
  __builtin_amdgcn_global_load_lds(
      (const __attribute__((address_space(1))) void*)g,
      (__attribute__((address_space(3))) void*)l, 4, 0, 0);
}

// ---------------- cast x (f32 -> bf16), vectorized x4 ----------------
__global__ __launch_bounds__(256) void castx_kernel(const float* __restrict__ x,
                                                    u16* __restrict__ xb) {
  int i = (blockIdx.x * 256 + threadIdx.x) * 4;
  f32x4 v = *(const f32x4*)&x[i];
  u16x4 o = { f2bf(v[0]), f2bf(v[1]), f2bf(v[2]), f2bf(v[3]) };
  *(u16x4*)&xb[i] = o;
}

// ------------- transpose + cast: W[R][C] f32 -> WT[C][R] bf16 -------------
__global__ __launch_bounds__(256) void tcast_kernel(const float* __restrict__ W,
                                                    u16* __restrict__ WT,
                                                    int R, int C) {
  __shared__ float tile[32][33];
  int c0 = blockIdx.x * 32, r0 = blockIdx.y * 32;
  int tx = threadIdx.x & 31, ty = threadIdx.x >> 5;  // 32 x 8
#pragma unroll
  for (int j = 0; j < 4; ++j)
    tile[ty + j * 8][tx] = W[(size_t)(r0 + ty + j * 8) * C + c0 + tx];
  __syncthreads();
#pragma unroll
  for (int j = 0; j < 4; ++j)
    WT[(size_t)(c0 + ty + j * 8) * R + r0 + tx] = f2bf(tile[tx][ty + j * 8]);
}

// ---------------- NT GEMM: A[M,K] bf16, B[N,K] bf16 -> C[M,N] f32 ----------------
__global__ __launch_bounds__(256) void gemm_bt_kernel(const u16* __restrict__ A,
                                                      const u16* __restrict__ B,
                                                      float* __restrict__ C,
                                                      int M, int N, int K) {
  __shared__ short As[128 * 72];
  __shared__ short Bs[128 * 72];
  const int tid = threadIdx.x;
  const int lane = tid & 63, wave = tid >> 6;
  const int wm = wave >> 1, wn = wave & 1;
  const int m0 = blockIdx.y * 128, n0 = blockIdx.x * 128;
  const int l15 = lane & 15, lhi = lane >> 4;

  f32x4 acc[4][4] = {};

  for (int k0 = 0; k0 < K; k0 += 64) {
    __syncthreads();
#pragma unroll
    for (int i = 0; i < 4; ++i) {
      int chunk = tid + i * 256;
      int row = chunk >> 3;
      int kc = (chunk & 7) * 8;
      *(bf16x8*)&As[row * 72 + kc] =
          *(const bf16x8*)&A[(size_t)(m0 + row) * K + k0 + kc];
      *(bf16x8*)&Bs[row * 72 + kc] =
          *(const bf16x8*)&B[(size_t)(n0 + row) * K + k0 + kc];
    }
    __syncthreads();
#pragma unroll
    for (int kk = 0; kk < 64; kk += 32) {
      const int koff = kk + lhi * 8;
      bf16x8 a[4], b[4];
#pragma unroll
      for (int m = 0; m < 4; ++m)
        a[m] = *(const bf16x8*)&As[(wm * 64 + m * 16 + l15) * 72 + koff];
#pragma unroll
      for (int n = 0; n < 4; ++n)
        b[n] = *(const bf16x8*)&Bs[(wn * 64 + n * 16 + l15) * 72 + koff];
#pragma unroll
      for (int m = 0; m < 4; ++m)
#pragma unroll
        for (int n = 0; n < 4; ++n)
          acc[m][n] = __builtin_amdgcn_mfma_f32_16x16x32_bf16(a[m], b[n], acc[m][n], 0, 0, 0);
    }
  }
#pragma unroll
  for (int m = 0; m < 4; ++m)
#pragma unroll
    for (int n = 0; n < 4; ++n)
#pragma unroll
      for (int j = 0; j < 4; ++j) {
        int row = m0 + wm * 64 + m * 16 + lhi * 4 + j;
        int col = n0 + wn * 64 + n * 16 + l15;
        C[(size_t)row * N + col] = acc[m][n][j];
      }
}

// ---------------- causal depthwise conv (K=4) + SiLU ----------------
__global__ __launch_bounds__(256) void conv_silu_kernel(const float* __restrict__ qkv,
                                                        const float* __restrict__ cw,
                                                        float* __restrict__ qkvc) {
  int idx = blockIdx.x * 256 + threadIdx.x;
  int l = idx / CONVD, c = idx - l * CONVD;
  f32x4 w = *(const f32x4*)&cw[c * 4];
  float s = qkv[idx] * w[3];
  if (l >= 1) s += qkv[idx - CONVD] * w[2];
  if (l >= 2) s += qkv[idx - 2 * CONVD] * w[1];
  if (l >= 3) s += qkv[idx - 3 * CONVD] * w[0];
  qkvc[idx] = s / (1.f + expf(-s));
}

// -------- beta/eg gates, written TRANSPOSED: egT/btT[h*1024 + l] --------
__global__ __launch_bounds__(128) void betag_kernel(const float* __restrict__ x,
                                                    const float* __restrict__ Wb,
                                                    const float* __restrict__ Wa,
                                                    const float* __restrict__ A_log,
                                                    const float* __restrict__ dt_bias,
                                                    float* __restrict__ btT,
                                                    float* __restrict__ egT) {
  int l = blockIdx.x;
  __shared__ float xs[IDIM_];
  __shared__ float redb[128], reda[128];
  for (int i = threadIdx.x; i < IDIM_; i += 128) xs[i] = x[(size_t)l * IDIM_ + i];
  __syncthreads();
  int h = threadIdx.x & 15, part = threadIdx.x >> 4;
  float sb = 0.f, sa = 0.f;
  int d0 = part * 256;
  for (int d = d0; d < d0 + 256; ++d) {
    float xv = xs[d];
    sb += xv * Wb[d * 16 + h];
    sa += xv * Wa[d * 16 + h];
  }
  redb[threadIdx.x] = sb;
  reda[threadIdx.x] = sa;
  __syncthreads();
  if (threadIdx.x < 16) {
    float b = 0.f, a = 0.f;
#pragma unroll
    for (int p = 0; p < 8; ++p) { b += redb[p * 16 + h]; a += reda[p * 16 + h]; }
    btT[h * L_SEQ + l] = 1.f / (1.f + expf(-b));
    float dtv = a + dt_bias[h];
    dtv = (dtv > 20.f) ? dtv : log1pf(expf(dtv));
    float g = -expf(A_log[h]) * dtv;
    egT[h * L_SEQ + l] = expf(g);
  }
}

// ---- l2norm q (with scale) and k; repack to qn/kn[h][l][dk] ----
__global__ __launch_bounds__(256) void l2norm_kernel(const float* __restrict__ qkvc,
                                                     float* __restrict__ qn,
                                                     float* __restrict__ kn) {
  int wid = blockIdx.x * 4 + (threadIdx.x >> 6);
  int lane = threadIdx.x & 63;
  int which = wid & 1;
  int lh = wid >> 1;
  int l = lh >> 4, h = lh & 15;
  const float* base = qkvc + (size_t)l * CONVD + which * KEYD + h * 128;
  f32x2 v = *(const f32x2*)&base[lane * 2];
  float ss = v[0] * v[0] + v[1] * v[1];
#pragma unroll
  for (int s = 1; s < 64; s <<= 1) ss += __shfl_xor(ss, s);
  float sc = 1.f / sqrtf(ss + 1e-6f);
  if (which == 0) sc *= 0.08838834764831845f;  // DK^-0.5
  v[0] *= sc; v[1] *= sc;
  float* dst = (which ? kn : qn) + ((size_t)h * L_SEQ + l) * 128 + lane * 2;
  *(f32x2*)dst = v;
}

// ---- transpose v slice of qkvc -> vT[c][l], c = h*128+dv ----
__global__ __launch_bounds__(256) void vtrans_kernel(const float* __restrict__ qkvc,
                                                     float* __restrict__ vT) {
  __shared__ float tile[32][33];
  int c0 = blockIdx.x * 32, l0 = blockIdx.y * 32;
  int tx = threadIdx.x & 31, ty = threadIdx.x >> 5;
#pragma unroll
  for (int j = 0; j < 4; ++j)
    tile[ty + j * 8][tx] = qkvc[(size_t)(l0 + ty + j * 8) * CONVD + 2 * KEYD + c0 + tx];
  __syncthreads();
#pragma unroll
  for (int j = 0; j < 4; ++j)
    vT[(size_t)(c0 + ty + j * 8) * L_SEQ + l0 + tx] = tile[tx][ty + j * 8];
}

// ---------------- sequential delta-rule scan v2 ----------------
// block = 256 thr = 4 waves = 16 columns (one head, 16 consecutive dv).
// 16 lanes per column, 8 dk-state regs/lane. DPP butterfly, LDS chunk staging.
__global__ __launch_bounds__(256) void scan_kernel(const float* __restrict__ qn,
                                                   const float* __restrict__ kn,
                                                   const float* __restrict__ vT,
                                                   const float* __restrict__ egT,
                                                   const float* __restrict__ btT,
                                                   float* __restrict__ oatt) {
  __shared__ alignas(16) float qs[2][CH][128];
  __shared__ alignas(16) float ks[2][CH][128];
  __shared__ float vs[2][16][CH];
  __shared__ float es[2][CH];
  __shared__ float bs[2][CH];

  const int tid = threadIdx.x;
  const int wave = tid >> 6, lane = tid & 63;
  const int g = lane >> 4, dk_sub = lane & 15;
  const int head = blockIdx.x & 15;           // head = b%16 -> XCD c gets heads {c, c+8}
  const int dv0 = (blockIdx.x >> 4) * 16;
  const int col_local = wave * 4 + g;
  const int dv = dv0 + col_local;

  const float* qh = qn + (size_t)head * L_SEQ * 128;
  const float* kh = kn + (size_t)head * L_SEQ * 128;

  auto stage = [&](int chunk, int buf) {
    const int l0 = chunk * CH;
    const float* qg = qh + (size_t)l0 * 128;
    const float* kg = kh + (size_t)l0 * 128;
#pragma unroll
    for (int i = 0; i < 2; ++i) {
      int seg = i * 4 + wave;             // 8 segments of 256 floats
      int off = seg * 256 + lane * 4;
      gl_lds16(qg + off, &qs[buf][0][0] + seg * 256);
      gl_lds16(kg + off, &ks[buf][0][0] + seg * 256);
    }
    // v chunk: 256 floats, LDS dest linear in tid, global per-lane
    // column for lane = head*128 + dv0 + (tid>>4)  (head offset!)
    gl_lds4(vT + (size_t)(head * 128 + dv0 + (tid >> 4)) * L_SEQ + l0 + (tid & 15),
            &vs[buf][0][0] + wave * 64);
    if (tid < CH) es[buf][tid] = egT[head * L_SEQ + l0 + tid];
    else if (tid < 2 * CH) bs[buf][tid - CH] = btT[head * L_SEQ + l0 + tid - CH];
  };

  stage(0, 0);
  __syncthreads();

  float M[8] = {0.f, 0.f, 0.f, 0.f, 0.f, 0.f, 0.f, 0.f};
  const int dkb = dk_sub * 8;

#pragma unroll 1
  for (int c = 0; c < NCH; ++c) {
    const int buf = c & 1;
    if (c + 1 < NCH) stage(c + 1, buf ^ 1);

    f32x4 q4[2][2], k4[2][2];
    float vv[2], ee[2], bb[2];
    q4[0][0] = *(const f32x4*)&qs[buf][0][dkb];
    q4[0][1] = *(const f32x4*)&qs[buf][0][dkb + 4];
    k4[0][0] = *(const f32x4*)&ks[buf][0][dkb];
    k4[0][1] = *(const f32x4*)&ks[buf][0][dkb + 4];
    vv[0] = vs[buf][col_local][0];
    ee[0] = es[buf][0];
    bb[0] = bs[buf][0];

#pragma unroll
    for (int s = 0; s < CH; ++s) {
      const int cur = s & 1, nxt = cur ^ 1;
      if (s + 1 < CH) {
        q4[nxt][0] = *(const f32x4*)&qs[buf][s + 1][dkb];
        q4[nxt][1] = *(const f32x4*)&qs[buf][s + 1][dkb + 4];
        k4[nxt][0] = *(const f32x4*)&ks[buf][s + 1][dkb];
        k4[nxt][1] = *(const f32x4*)&ks[buf][s + 1][dkb + 4];
        vv[nxt] = vs[buf][col_local][s + 1];
        ee[nxt] = es[buf][s + 1];
        bb[nxt] = bs[buf][s + 1];
      }
      const float e = ee[cur], b = bb[cur], v = vv[cur];
      float kk[8] = {k4[cur][0][0], k4[cur][0][1], k4[cur][0][2], k4[cur][0][3],
                     k4[cur][1][0], k4[cur][1][1], k4[cur][1][2], k4[cur][1][3]};
      float qq[8] = {q4[cur][0][0], q4[cur][0][1], q4[cur][0][2], q4[cur][0][3],
                     q4[cur][1][0], q4[cur][1][1], q4[cur][1][2], q4[cur][1][3]};
      float em[8];
#pragma unroll
      for (int i = 0; i < 8; ++i) em[i] = e * M[i];
      float skm0 = kk[0] * M[0], skm1 = kk[1] * M[1];
      float sqm0 = qq[0] * M[0], sqm1 = qq[1] * M[1];
      float sqk0 = qq[0] * kk[0], sqk1 = qq[1] * kk[1];
#pragma unroll
      for (int i = 2; i < 8; i += 2) {
        skm0 = fmaf(kk[i], M[i], skm0);
        skm1 = fmaf(kk[i + 1], M[i + 1], skm1);
        sqm0 = fmaf(qq[i], M[i], sqm0);
        sqm1 = fmaf(qq[i + 1], M[i + 1], sqm1);
        sqk0 = fmaf(qq[i], kk[i], sqk0);
        sqk1 = fmaf(qq[i + 1], kk[i + 1], sqk1);
      }
      float skm = red16(skm0 + skm1);
      float sqm = red16(sqm0 + sqm1);
      float sqk = red16(sqk0 + sqk1);
      float dl = (v - e * skm) * b;       // delta
      float o = fmaf(sqk, dl, e * sqm);   // q . M_new
      if (dk_sub == 0)
        oatt[(size_t)((c * CH + s) * 16 + head) * 128 + dv] = o;
#pragma unroll
      for (int i = 0; i < 8; ++i) M[i] = fmaf(kk[i], dl, em[i]);
    }
    __syncthreads();
  }
}

// ---------------- gated RMSNorm -> bf16 ----------------
__global__ __launch_bounds__(256) void grms_kernel(const float* __restrict__ oatt,
                                                   const float* __restrict__ z,
                                                   const float* __restrict__ norm_w,
                                                   u16* __restrict__ gn) {
  int wid = blockIdx.x * 4 + (threadIdx.x >> 6);
  int lane = threadIdx.x & 63;
  int l = wid >> 4, h = wid & 15;
  const float* o = oatt + (size_t)wid * 128;
  f32x2 ov = *(const f32x2*)&o[lane * 2];
  float ss = ov[0] * ov[0] + ov[1] * ov[1];
#pragma unroll
  for (int s = 1; s < 64; s <<= 1) ss += __shfl_xor(ss, s);
  float r = 1.f / sqrtf(ss * (1.f / 128.f) + 1e-6f);
  const float* zp = z + (size_t)l * VALD + h * 128;
  f32x2 zv = *(const f32x2*)&zp[lane * 2];
  u16 r0, r1;
  {
    float sil = zv[0] / (1.f + expf(-zv[0]));
    r0 = f2bf(ov[0] * r * norm_w[lane * 2] * sil);
    float sil1 = zv[1] / (1.f + expf(-zv[1]));
    r1 = f2bf(ov[1] * r * norm_w[lane * 2 + 1] * sil1);
  }
  u16* dst = gn + (size_t)l * VALD + h * 128 + lane * 2;
  dst[0] = r0; dst[1] = r1;
}

extern "C" void kernel_launch(void* const* d_in, const int* in_sizes, int n_in,
                              void* d_out, int out_size, void* d_ws, size_t ws_size,
                              hipStream_t stream) {
  const float* x      = (const float*)d_in[0];
  const float* Wqkv   = (const float*)d_in[1];
  const float* Wz     = (const float*)d_in[2];
  const float* Wb     = (const float*)d_in[3];
  const float* Wa     = (const float*)d_in[4];
  const float* conv_w = (const float*)d_in[5];
  const float* A_log  = (const float*)d_in[6];
  const float* dt_bias= (const float*)d_in[7];
  const float* norm_w = (const float*)d_in[8];
  const float* Wout   = (const float*)d_in[9];
  float* out = (float*)d_out;

  char* ws = (char*)d_ws;
  size_t off = 0;
  auto alloc = [&](size_t bytes) {
    void* p = ws + off;
    off = (off + bytes + 255) & ~(size_t)255;
    return p;
  };
  u16* xb     = (u16*)alloc((size_t)L_SEQ * IDIM_ * 2);
  u16* WqkvT  = (u16*)alloc((size_t)CONVD * IDIM_ * 2);
  u16* WzT    = (u16*)alloc((size_t)VALD * IDIM_ * 2);
  u16* WoutT  = (u16*)alloc((size_t)IDIM_ * VALD * 2);
  float* qkv  = (float*)alloc((size_t)L_SEQ * CONVD * 4);
  float* qkvc = (float*)alloc((size_t)L_SEQ * CONVD * 4);
  float* zbuf = (float*)alloc((size_t)L_SEQ * VALD * 4);
  float* btT  = (float*)alloc((size_t)L_SEQ * H_ * 4);
  float* egT  = (float*)alloc((size_t)L_SEQ * H_ * 4);
  float* oatt = (float*)alloc((size_t)L_SEQ * H_ * DV_ * 4);
  u16* gn     = (u16*)alloc((size_t)L_SEQ * VALD * 2);

  // qn/kn/vT reuse the dead qkv buffer after conv (exact 24MB fit in 24MB)
  float* qn = qkv;
  float* kn = qn + (size_t)H_ * L_SEQ * 128;
  float* vT = kn + (size_t)H_ * L_SEQ * 128;

  // casts / transposes
  castx_kernel<<<(L_SEQ * IDIM_) / 1024, 256, 0, stream>>>(x, xb);
  tcast_kernel<<<dim3(CONVD / 32, IDIM_ / 32), 256, 0, stream>>>(Wqkv, WqkvT, IDIM_, CONVD);
  tcast_kernel<<<dim3(VALD / 32, IDIM_ / 32), 256, 0, stream>>>(Wz, WzT, IDIM_, VALD);
  tcast_kernel<<<dim3(IDIM_ / 32, VALD / 32), 256, 0, stream>>>(Wout, WoutT, VALD, IDIM_);

  // projections
  gemm_bt_kernel<<<dim3(CONVD / 128, L_SEQ / 128), 256, 0, stream>>>(xb, WqkvT, qkv, L_SEQ, CONVD, IDIM_);
  gemm_bt_kernel<<<dim3(VALD / 128, L_SEQ / 128), 256, 0, stream>>>(xb, WzT, zbuf, L_SEQ, VALD, IDIM_);

  // conv + silu, gates
  conv_silu_kernel<<<(L_SEQ * CONVD) / 256, 256, 0, stream>>>(qkv, conv_w, qkvc);
  betag_kernel<<<L_SEQ, 128, 0, stream>>>(x, Wb, Wa, A_log, dt_bias, btT, egT);

  // repack: q/k l2norm -> [h][l][dk] (overwrites dead qkv buf), v -> [h][dv][l]
  l2norm_kernel<<<(L_SEQ * H_ * 2) / 4, 256, 0, stream>>>(qkvc, qn, kn);
  vtrans_kernel<<<dim3(VALD / 32, L_SEQ / 32), 256, 0, stream>>>(qkvc, vT);

  // sequential scan
  scan_kernel<<<H_ * (DV_ / 16), 256, 0, stream>>>(qn, kn, vT, egT, btT, oatt);

  // gated rmsnorm + final projection
  grms_kernel<<<(L_SEQ * H_) / 4, 256, 0, stream>>>(oatt, zbuf, norm_w, gn);
  gemm_bt_kernel<<<dim3(IDIM_ / 128, L_SEQ / 128), 256, 0, stream>>>(gn, WoutT, out, L_SEQ, IDIM_, VALD);
}

// Round 4
// 429.951 us; speedup vs baseline: 2.0556x; 1.0004x over previous
//
#include <hip/hip_runtime.h>

typedef short bf16x8 __attribute__((ext_vector_type(8)));
typedef float f32x4 __attribute__((ext_vector_type(4)));
typedef float f32x2 __attribute__((ext_vector_type(2)));
typedef unsigned short u16;
typedef u16 u16x4 __attribute__((ext_vector_type(4)));

#define L_SEQ 1024
#define IDIM_ 2048
#define H_ 16
#define DK_ 128
#define DV_ 128
#define KEYD 2048
#define VALD 2048
#define CONVD 6144
#define CH 16
#define NCH (L_SEQ / CH)

__device__ __forceinline__ u16 f2bf(float f) {
  union { float f; unsigned u; } v; v.f = f;
  unsigned r = v.u + 0x7FFF + ((v.u >> 16) & 1);  // RNE
  return (u16)(r >> 16);
}

// 16-lane allreduce, all-DPP (VALU only): xor1, xor2, row_half_mirror(==xor4
// once quads uniform), row_mirror(==xor8 once octets uniform)
__device__ __forceinline__ float red16(float x) {
  union U { float f; int i; } a, t;
  a.f = x;
  t.i = __builtin_amdgcn_update_dpp(0, a.i, 0xB1, 0xF, 0xF, true); a.f += t.f;
  t.i = __builtin_amdgcn_update_dpp(0, a.i, 0x4E, 0xF, 0xF, true); a.f += t.f;
  t.i = __builtin_amdgcn_update_dpp(0, a.i, 0x141, 0xF, 0xF, true); a.f += t.f;
  t.i = __builtin_amdgcn_update_dpp(0, a.i, 0x140, 0xF, 0xF, true); a.f += t.f;
  return a.f;
}

// lane ^ 16 within each 32-lane group (BitMode xor=0x10, and=0x1F)
__device__ __forceinline__ float swz16(float x) {
  return __int_as_float(__builtin_amdgcn_ds_swizzle(__float_as_int(x), 0x401F));
}

__device__ __forceinline__ void gl_lds16(const float* g, float* l) {
  __builtin_amdgcn_global_load_lds(
      (const __attribute__((address_space(1))) void*)g,
      (__attribute__((address_space(3))) void*)l, 16, 0, 0);
}
__device__ __forceinline__ void gl_lds4(const float* g, float* l) {
  __builtin_amdgcn_global_load_lds(
      (const __attribute__((address_space(1))) void*)g,
      (__attribute__((address_space(3))) void*)l, 4, 0, 0);
}

// ---------------- cast x (f32 -> bf16), vectorized x4 ----------------
__global__ __launch_bounds__(256) void castx_kernel(const float* __restrict__ x,
                                                    u16* __restrict__ xb) {
  int i = (blockIdx.x * 256 + threadIdx.x) * 4;
  f32x4 v = *(const f32x4*)&x[i];
  u16x4 o = { f2bf(v[0]), f2bf(v[1]), f2bf(v[2]), f2bf(v[3]) };
  *(u16x4*)&xb[i] = o;
}

// ------------- transpose + cast: W[R][C] f32 -> WT[C][R] bf16 -------------
__global__ __launch_bounds__(256) void tcast_kernel(const float* __restrict__ W,
                                                    u16* __restrict__ WT,
                                                    int R, int C) {
  __shared__ float tile[32][33];
  int c0 = blockIdx.x * 32, r0 = blockIdx.y * 32;
  int tx = threadIdx.x & 31, ty = threadIdx.x >> 5;  // 32 x 8
#pragma unroll
  for (int j = 0; j < 4; ++j)
    tile[ty + j * 8][tx] = W[(size_t)(r0 + ty + j * 8) * C + c0 + tx];
  __syncthreads();
#pragma unroll
  for (int j = 0; j < 4; ++j)
    WT[(size_t)(c0 + ty + j * 8) * R + r0 + tx] = f2bf(tile[tx][ty + j * 8]);
}

// ---------------- NT GEMM: A[M,K] bf16, B[N,K] bf16 -> C[M,N] f32 ----------------
__global__ __launch_bounds__(256) void gemm_bt_kernel(const u16* __restrict__ A,
                                                      const u16* __restrict__ B,
                                                      float* __restrict__ C,
                                                      int M, int N, int K) {
  __shared__ short As[128 * 72];
  __shared__ short Bs[128 * 72];
  const int tid = threadIdx.x;
  const int lane = tid & 63, wave = tid >> 6;
  const int wm = wave >> 1, wn = wave & 1;
  const int m0 = blockIdx.y * 128, n0 = blockIdx.x * 128;
  const int l15 = lane & 15, lhi = lane >> 4;

  f32x4 acc[4][4] = {};

  for (int k0 = 0; k0 < K; k0 += 64) {
    __syncthreads();
#pragma unroll
    for (int i = 0; i < 4; ++i) {
      int chunk = tid + i * 256;
      int row = chunk >> 3;
      int kc = (chunk & 7) * 8;
      *(bf16x8*)&As[row * 72 + kc] =
          *(const bf16x8*)&A[(size_t)(m0 + row) * K + k0 + kc];
      *(bf16x8*)&Bs[row * 72 + kc] =
          *(const bf16x8*)&B[(size_t)(n0 + row) * K + k0 + kc];
    }
    __syncthreads();
#pragma unroll
    for (int kk = 0; kk < 64; kk += 32) {
      const int koff = kk + lhi * 8;
      bf16x8 a[4], b[4];
#pragma unroll
      for (int m = 0; m < 4; ++m)
        a[m] = *(const bf16x8*)&As[(wm * 64 + m * 16 + l15) * 72 + koff];
#pragma unroll
      for (int n = 0; n < 4; ++n)
        b[n] = *(const bf16x8*)&Bs[(wn * 64 + n * 16 + l15) * 72 + koff];
#pragma unroll
      for (int m = 0; m < 4; ++m)
#pragma unroll
        for (int n = 0; n < 4; ++n)
          acc[m][n] = __builtin_amdgcn_mfma_f32_16x16x32_bf16(a[m], b[n], acc[m][n], 0, 0, 0);
    }
  }
#pragma unroll
  for (int m = 0; m < 4; ++m)
#pragma unroll
    for (int n = 0; n < 4; ++n)
#pragma unroll
      for (int j = 0; j < 4; ++j) {
        int row = m0 + wm * 64 + m * 16 + lhi * 4 + j;
        int col = n0 + wn * 64 + n * 16 + l15;
        C[(size_t)row * N + col] = acc[m][n][j];
      }
}

// ---------------- causal depthwise conv (K=4) + SiLU ----------------
__global__ __launch_bounds__(256) void conv_silu_kernel(const float* __restrict__ qkv,
                                                        const float* __restrict__ cw,
                                                        float* __restrict__ qkvc) {
  int idx = blockIdx.x * 256 + threadIdx.x;
  int l = idx / CONVD, c = idx - l * CONVD;
  f32x4 w = *(const f32x4*)&cw[c * 4];
  float s = qkv[idx] * w[3];
  if (l >= 1) s += qkv[idx - CONVD] * w[2];
  if (l >= 2) s += qkv[idx - 2 * CONVD] * w[1];
  if (l >= 3) s += qkv[idx - 3 * CONVD] * w[0];
  qkvc[idx] = s / (1.f + expf(-s));
}

// -------- beta/eg gates, written TRANSPOSED: egT/btT[h*1024 + l] --------
__global__ __launch_bounds__(128) void betag_kernel(const float* __restrict__ x,
                                                    const float* __restrict__ Wb,
                                                    const float* __restrict__ Wa,
                                                    const float* __restrict__ A_log,
                                                    const float* __restrict__ dt_bias,
                                                    float* __restrict__ btT,
                                                    float* __restrict__ egT) {
  int l = blockIdx.x;
  __shared__ float xs[IDIM_];
  __shared__ float redb[128], reda[128];
  for (int i = threadIdx.x; i < IDIM_; i += 128) xs[i] = x[(size_t)l * IDIM_ + i];
  __syncthreads();
  int h = threadIdx.x & 15, part = threadIdx.x >> 4;
  float sb = 0.f, sa = 0.f;
  int d0 = part * 256;
  for (int d = d0; d < d0 + 256; ++d) {
    float xv = xs[d];
    sb += xv * Wb[d * 16 + h];
    sa += xv * Wa[d * 16 + h];
  }
  redb[threadIdx.x] = sb;
  reda[threadIdx.x] = sa;
  __syncthreads();
  if (threadIdx.x < 16) {
    float b = 0.f, a = 0.f;
#pragma unroll
    for (int p = 0; p < 8; ++p) { b += redb[p * 16 + h]; a += reda[p * 16 + h]; }
    btT[h * L_SEQ + l] = 1.f / (1.f + expf(-b));
    float dtv = a + dt_bias[h];
    dtv = (dtv > 20.f) ? dtv : log1pf(expf(dtv));
    float g = -expf(A_log[h]) * dtv;
    egT[h * L_SEQ + l] = expf(g);
  }
}

// ---- l2norm q (scaled) + k, repack to [h][l][dk]; also qkT[h][l] = q.k ----
__global__ __launch_bounds__(256) void l2qk_kernel(const float* __restrict__ qkvc,
                                                   float* __restrict__ qn,
                                                   float* __restrict__ kn,
                                                   float* __restrict__ qkT) {
  int wid = blockIdx.x * 4 + (threadIdx.x >> 6);  // 16384 waves: l*16+h
  int lane = threadIdx.x & 63;
  int l = wid >> 4, h = wid & 15;
  const float* qb = qkvc + (size_t)l * CONVD + h * 128;
  const float* kb = qb + KEYD;
  f32x2 qv = *(const f32x2*)&qb[lane * 2];
  f32x2 kv = *(const f32x2*)&kb[lane * 2];
  float ssq = qv[0] * qv[0] + qv[1] * qv[1];
  float ssk = kv[0] * kv[0] + kv[1] * kv[1];
#pragma unroll
  for (int s = 1; s < 64; s <<= 1) {
    ssq += __shfl_xor(ssq, s);
    ssk += __shfl_xor(ssk, s);
  }
  float scq = 0.08838834764831845f / sqrtf(ssq + 1e-6f);  // * DK^-0.5
  float sck = 1.f / sqrtf(ssk + 1e-6f);
  qv[0] *= scq; qv[1] *= scq;
  kv[0] *= sck; kv[1] *= sck;
  size_t base = ((size_t)h * L_SEQ + l) * 128 + lane * 2;
  *(f32x2*)&qn[base] = qv;
  *(f32x2*)&kn[base] = kv;
  float qk = qv[0] * kv[0] + qv[1] * kv[1];
#pragma unroll
  for (int s = 1; s < 64; s <<= 1) qk += __shfl_xor(qk, s);
  if (lane == 0) qkT[h * L_SEQ + l] = qk;
}

// ---- transpose v slice of qkvc -> vT[c][l], c = h*128+dv ----
__global__ __launch_bounds__(256) void vtrans_kernel(const float* __restrict__ qkvc,
                                                     float* __restrict__ vT) {
  __shared__ float tile[32][33];
  int c0 = blockIdx.x * 32, l0 = blockIdx.y * 32;
  int tx = threadIdx.x & 31, ty = threadIdx.x >> 5;
#pragma unroll
  for (int j = 0; j < 4; ++j)
    tile[ty + j * 8][tx] = qkvc[(size_t)(l0 + ty + j * 8) * CONVD + 2 * KEYD + c0 + tx];
  __syncthreads();
#pragma unroll
  for (int j = 0; j < 4; ++j)
    vT[(size_t)(c0 + ty + j * 8) * L_SEQ + l0 + tx] = tile[tx][ty + j * 8];
}

// ---------------- sequential delta-rule scan v3 ----------------
// P=32 lanes/col, 2 cols/wave, 4 waves/block = 8 cols (one head, 8 dv).
// grid = 256 blocks -> 1024 waves -> all 1024 SIMDs. qk precomputed (qkT).
__global__ __launch_bounds__(256) void scan_kernel(const float* __restrict__ qn,
                                                   const float* __restrict__ kn,
                                                   const float* __restrict__ vT,
                                                   const float* __restrict__ egT,
                                                   const float* __restrict__ btT,
                                                   const float* __restrict__ qkT,
                                                   float* __restrict__ oatt) {
  __shared__ alignas(16) float qs[2][CH][128];
  __shared__ alignas(16) float ks[2][CH][128];
  __shared__ float vs[2][8][CH];
  __shared__ alignas(16) float ebq[2][CH][4];

  const int tid = threadIdx.x;
  const int wave = tid >> 6, lane = tid & 63;
  const int half = lane >> 5;         // column within wave
  const int sub = lane & 31;          // dk sub-lane (4 floats each)
  const int head = blockIdx.x & 15;   // consecutive blocks -> different heads
  const int dv0 = (blockIdx.x >> 4) * 8;
  const int col_local = wave * 2 + half;
  const int dv = dv0 + col_local;

  const float* qh = qn + (size_t)head * L_SEQ * 128;
  const float* kh = kn + (size_t)head * L_SEQ * 128;

  auto stage = [&](int chunk, int buf) {
    const int l0 = chunk * CH;
    const float* qg = qh + (size_t)l0 * 128;
    const float* kg = kh + (size_t)l0 * 128;
#pragma unroll
    for (int i = 0; i < 2; ++i) {
      int seg = i * 4 + wave;           // 8 segments of 256 floats
      int off = seg * 256 + lane * 4;
      gl_lds16(qg + off, &qs[buf][0][0] + seg * 256);
      gl_lds16(kg + off, &ks[buf][0][0] + seg * 256);
    }
    if (wave < 2) {                     // v: 8 cols x CH steps = 128 floats
      int idx = wave * 64 + lane;       // col = idx>>4, step = idx&15
      gl_lds4(vT + (size_t)(head * 128 + dv0 + (idx >> 4)) * L_SEQ + l0 + (idx & 15),
              &vs[buf][0][0] + wave * 64);
    }
    if (tid < CH) {
      ebq[buf][tid][0] = egT[head * L_SEQ + l0 + tid];
      ebq[buf][tid][1] = btT[head * L_SEQ + l0 + tid];
      ebq[buf][tid][2] = qkT[head * L_SEQ + l0 + tid];
    }
  };

  stage(0, 0);
  __syncthreads();

  f32x4 Mv = {0.f, 0.f, 0.f, 0.f};
  const int dkb = sub * 4;

#pragma unroll 1
  for (int c = 0; c < NCH; ++c) {
    const int buf = c & 1;
    if (c + 1 < NCH) stage(c + 1, buf ^ 1);

    f32x4 qr[2], kr[2], eb[2];
    float vv[2];
    qr[0] = *(const f32x4*)&qs[buf][0][dkb];
    kr[0] = *(const f32x4*)&ks[buf][0][dkb];
    vv[0] = vs[buf][col_local][0];
    eb[0] = *(const f32x4*)&ebq[buf][0][0];

#pragma unroll
    for (int s = 0; s < CH; ++s) {
      const int cur = s & 1, nxt = cur ^ 1;
      if (s + 1 < CH) {
        qr[nxt] = *(const f32x4*)&qs[buf][s + 1][dkb];
        kr[nxt] = *(const f32x4*)&ks[buf][s + 1][dkb];
        vv[nxt] = vs[buf][col_local][s + 1];
        eb[nxt] = *(const f32x4*)&ebq[buf][s + 1][0];
      }
      const float e = eb[cur][0], b = eb[cur][1], qk = eb[cur][2], v = vv[cur];
      const f32x4 k4 = kr[cur], q4 = qr[cur];

      // dots on M_old (pairwise, depth 2 + combine)
      float skm0 = k4[0] * Mv[0], skm1 = k4[1] * Mv[1];
      float sqm0 = q4[0] * Mv[0], sqm1 = q4[1] * Mv[1];
      skm0 = fmaf(k4[2], Mv[2], skm0); skm1 = fmaf(k4[3], Mv[3], skm1);
      sqm0 = fmaf(q4[2], Mv[2], sqm0); sqm1 = fmaf(q4[3], Mv[3], sqm1);
      f32x4 em;
#pragma unroll
      for (int i = 0; i < 4; ++i) em[i] = e * Mv[i];
      float skm = red16(skm0 + skm1);
      float sqm = red16(sqm0 + sqm1);
      skm += swz16(skm);                // combine the two 16-rows of the col
      sqm += swz16(sqm);
      float dl = (v - e * skm) * b;     // delta
      float o = fmaf(qk, dl, e * sqm);  // q . M_new
      if (sub == 0)
        oatt[(size_t)((c * CH + s) * 16 + head) * 128 + dv] = o;
#pragma unroll
      for (int i = 0; i < 4; ++i) Mv[i] = fmaf(k4[i], dl, em[i]);
    }
    __syncthreads();
  }
}

// ---------------- gated RMSNorm -> bf16 ----------------
__global__ __launch_bounds__(256) void grms_kernel(const float* __restrict__ oatt,
                                                   const float* __restrict__ z,
                                                   const float* __restrict__ norm_w,
                                                   u16* __restrict__ gn) {
  int wid = blockIdx.x * 4 + (threadIdx.x >> 6);
  int lane = threadIdx.x & 63;
  int l = wid >> 4, h = wid & 15;
  const float* o = oatt + (size_t)wid * 128;
  f32x2 ov = *(const f32x2*)&o[lane * 2];
  float ss = ov[0] * ov[0] + ov[1] * ov[1];
#pragma unroll
  for (int s = 1; s < 64; s <<= 1) ss += __shfl_xor(ss, s);
  float r = 1.f / sqrtf(ss * (1.f / 128.f) + 1e-6f);
  const float* zp = z + (size_t)l * VALD + h * 128;
  f32x2 zv = *(const f32x2*)&zp[lane * 2];
  u16 r0, r1;
  {
    float sil = zv[0] / (1.f + expf(-zv[0]));
    r0 = f2bf(ov[0] * r * norm_w[lane * 2] * sil);
    float sil1 = zv[1] / (1.f + expf(-zv[1]));
    r1 = f2bf(ov[1] * r * norm_w[lane * 2 + 1] * sil1);
  }
  u16* dst = gn + (size_t)l * VALD + h * 128 + lane * 2;
  dst[0] = r0; dst[1] = r1;
}

extern "C" void kernel_launch(void* const* d_in, const int* in_sizes, int n_in,
                              void* d_out, int out_size, void* d_ws, size_t ws_size,
                              hipStream_t stream) {
  const float* x      = (const float*)d_in[0];
  const float* Wqkv   = (const float*)d_in[1];
  const float* Wz     = (const float*)d_in[2];
  const float* Wb     = (const float*)d_in[3];
  const float* Wa     = (const float*)d_in[4];
  const float* conv_w = (const float*)d_in[5];
  const float* A_log  = (const float*)d_in[6];
  const float* dt_bias= (const float*)d_in[7];
  const float* norm_w = (const float*)d_in[8];
  const float* Wout   = (const float*)d_in[9];
  float* out = (float*)d_out;

  char* ws = (char*)d_ws;
  size_t off = 0;
  auto alloc = [&](size_t bytes) {
    void* p = ws + off;
    off = (off + bytes + 255) & ~(size_t)255;
    return p;
  };
  u16* xb     = (u16*)alloc((size_t)L_SEQ * IDIM_ * 2);
  u16* WqkvT  = (u16*)alloc((size_t)CONVD * IDIM_ * 2);
  u16* WzT    = (u16*)alloc((size_t)VALD * IDIM_ * 2);
  u16* WoutT  = (u16*)alloc((size_t)IDIM_ * VALD * 2);
  float* qkv  = (float*)alloc((size_t)L_SEQ * CONVD * 4);
  float* qkvc = (float*)alloc((size_t)L_SEQ * CONVD * 4);
  float* zbuf = (float*)alloc((size_t)L_SEQ * VALD * 4);
  float* btT  = (float*)alloc((size_t)L_SEQ * H_ * 4);
  float* egT  = (float*)alloc((size_t)L_SEQ * H_ * 4);
  float* qkTb = (float*)alloc((size_t)L_SEQ * H_ * 4);
  float* oatt = (float*)alloc((size_t)L_SEQ * H_ * DV_ * 4);
  u16* gn     = (u16*)alloc((size_t)L_SEQ * VALD * 2);

  // qn/kn/vT reuse the dead qkv buffer after conv (exact 24MB fit)
  float* qn = qkv;
  float* kn = qn + (size_t)H_ * L_SEQ * 128;
  float* vT = kn + (size_t)H_ * L_SEQ * 128;

  // casts / transposes
  castx_kernel<<<(L_SEQ * IDIM_) / 1024, 256, 0, stream>>>(x, xb);
  tcast_kernel<<<dim3(CONVD / 32, IDIM_ / 32), 256, 0, stream>>>(Wqkv, WqkvT, IDIM_, CONVD);
  tcast_kernel<<<dim3(VALD / 32, IDIM_ / 32), 256, 0, stream>>>(Wz, WzT, IDIM_, VALD);
  tcast_kernel<<<dim3(IDIM_ / 32, VALD / 32), 256, 0, stream>>>(Wout, WoutT, VALD, IDIM_);

  // projections
  gemm_bt_kernel<<<dim3(CONVD / 128, L_SEQ / 128), 256, 0, stream>>>(xb, WqkvT, qkv, L_SEQ, CONVD, IDIM_);
  gemm_bt_kernel<<<dim3(VALD / 128, L_SEQ / 128), 256, 0, stream>>>(xb, WzT, zbuf, L_SEQ, VALD, IDIM_);

  // conv + silu, gates
  conv_silu_kernel<<<(L_SEQ * CONVD) / 256, 256, 0, stream>>>(qkv, conv_w, qkvc);
  betag_kernel<<<L_SEQ, 128, 0, stream>>>(x, Wb, Wa, A_log, dt_bias, btT, egT);

  // repack: q/k l2norm + qk scalar -> [h][l][dk] / qkT[h][l]; v -> [h*128+dv][l]
  l2qk_kernel<<<(L_SEQ * H_) / 4, 256, 0, stream>>>(qkvc, qn, kn, qkTb);
  vtrans_kernel<<<dim3(VALD / 32, L_SEQ / 32), 256, 0, stream>>>(qkvc, vT);

  // sequential scan (256 blocks, 1024 waves)
  scan_kernel<<<H_ * (DV_ / 8), 256, 0, stream>>>(qn, kn, vT, egT, btT, qkTb, oatt);

  // gated rmsnorm + final projection
  grms_kernel<<<(L_SEQ * H_) / 4, 256, 0, stream>>>(oatt, zbuf, norm_w, gn);
  gemm_bt_kernel<<<dim3(IDIM_ / 128, L_SEQ / 128), 256, 0, stream>>>(gn, WoutT, out, L_SEQ, IDIM_, VALD);
}

// Round 6
// 395.138 us; speedup vs baseline: 2.2368x; 1.0881x over previous
//
#include <hip/hip_runtime.h>

typedef short bf16x8 __attribute__((ext_vector_type(8)));
typedef float f32x4 __attribute__((ext_vector_type(4)));
typedef float f32x2 __attribute__((ext_vector_type(2)));
typedef unsigned short u16;
typedef u16 u16x4 __attribute__((ext_vector_type(4)));

#define L_SEQ 1024
#define IDIM_ 2048
#define H_ 16
#define DK_ 128
#define DV_ 128
#define KEYD 2048
#define VALD 2048
#define CONVD 6144
#define CH 16
#define NCH (L_SEQ / CH)

__device__ __forceinline__ u16 f2bf(float f) {
  union { float f; unsigned u; } v; v.f = f;
  unsigned r = v.u + 0x7FFF + ((v.u >> 16) & 1);  // RNE
  return (u16)(r >> 16);
}

// 16-lane allreduce, all-DPP (VALU only): xor1, xor2, row_half_mirror(==xor4
// once quads uniform), row_mirror(==xor8 once octets uniform). Verified R3/R4.
__device__ __forceinline__ float red16(float x) {
  union U { float f; int i; } a, t;
  a.f = x;
  t.i = __builtin_amdgcn_update_dpp(0, a.i, 0xB1, 0xF, 0xF, true); a.f += t.f;
  t.i = __builtin_amdgcn_update_dpp(0, a.i, 0x4E, 0xF, 0xF, true); a.f += t.f;
  t.i = __builtin_amdgcn_update_dpp(0, a.i, 0x141, 0xF, 0xF, true); a.f += t.f;
  t.i = __builtin_amdgcn_update_dpp(0, a.i, 0x140, 0xF, 0xF, true); a.f += t.f;
  return a.f;
}

__device__ __forceinline__ void gl_lds16(const float* g, float* l) {
  __builtin_amdgcn_global_load_lds(
      (const __attribute__((address_space(1))) void*)g,
      (__attribute__((address_space(3))) void*)l, 16, 0, 0);
}
__device__ __forceinline__ void gl_lds4(const float* g, float* l) {
  __builtin_amdgcn_global_load_lds(
      (const __attribute__((address_space(1))) void*)g,
      (__attribute__((address_space(3))) void*)l, 4, 0, 0);
}

// ---------------- cast x (f32 -> bf16), vectorized x4 ----------------
__global__ __launch_bounds__(256) void castx_kernel(const float* __restrict__ x,
                                                    u16* __restrict__ xb) {
  int i = (blockIdx.x * 256 + threadIdx.x) * 4;
  f32x4 v = *(const f32x4*)&x[i];
  u16x4 o = { f2bf(v[0]), f2bf(v[1]), f2bf(v[2]), f2bf(v[3]) };
  *(u16x4*)&xb[i] = o;
}

// ------------- transpose + cast: W[R][C] f32 -> WT[C][R] bf16 -------------
__global__ __launch_bounds__(256) void tcast_kernel(const float* __restrict__ W,
                                                    u16* __restrict__ WT,
                                                    int R, int C) {
  __shared__ float tile[32][33];
  int c0 = blockIdx.x * 32, r0 = blockIdx.y * 32;
  int tx = threadIdx.x & 31, ty = threadIdx.x >> 5;  // 32 x 8
#pragma unroll
  for (int j = 0; j < 4; ++j)
    tile[ty + j * 8][tx] = W[(size_t)(r0 + ty + j * 8) * C + c0 + tx];
  __syncthreads();
#pragma unroll
  for (int j = 0; j < 4; ++j)
    WT[(size_t)(c0 + ty + j * 8) * R + r0 + tx] = f2bf(tile[tx][ty + j * 8]);
}

// ---------------- NT GEMM: A[M,K] bf16, B[N,K] bf16 -> C[M,N] f32 ----------------
__global__ __launch_bounds__(256) void gemm_bt_kernel(const u16* __restrict__ A,
                                                      const u16* __restrict__ B,
                                                      float* __restrict__ C,
                                                      int M, int N, int K) {
  __shared__ short As[128 * 72];
  __shared__ short Bs[128 * 72];
  const int tid = threadIdx.x;
  const int lane = tid & 63, wave = tid >> 6;
  const int wm = wave >> 1, wn = wave & 1;
  const int m0 = blockIdx.y * 128, n0 = blockIdx.x * 128;
  const int l15 = lane & 15, lhi = lane >> 4;

  f32x4 acc[4][4] = {};

  for (int k0 = 0; k0 < K; k0 += 64) {
    __syncthreads();
#pragma unroll
    for (int i = 0; i < 4; ++i) {
      int chunk = tid + i * 256;
      int row = chunk >> 3;
      int kc = (chunk & 7) * 8;
      *(bf16x8*)&As[row * 72 + kc] =
          *(const bf16x8*)&A[(size_t)(m0 + row) * K + k0 + kc];
      *(bf16x8*)&Bs[row * 72 + kc] =
          *(const bf16x8*)&B[(size_t)(n0 + row) * K + k0 + kc];
    }
    __syncthreads();
#pragma unroll
    for (int kk = 0; kk < 64; kk += 32) {
      const int koff = kk + lhi * 8;
      bf16x8 a[4], b[4];
#pragma unroll
      for (int m = 0; m < 4; ++m)
        a[m] = *(const bf16x8*)&As[(wm * 64 + m * 16 + l15) * 72 + koff];
#pragma unroll
      for (int n = 0; n < 4; ++n)
        b[n] = *(const bf16x8*)&Bs[(wn * 64 + n * 16 + l15) * 72 + koff];
#pragma unroll
      for (int m = 0; m < 4; ++m)
#pragma unroll
        for (int n = 0; n < 4; ++n)
          acc[m][n] = __builtin_amdgcn_mfma_f32_16x16x32_bf16(a[m], b[n], acc[m][n], 0, 0, 0);
    }
  }
#pragma unroll
  for (int m = 0; m < 4; ++m)
#pragma unroll
    for (int n = 0; n < 4; ++n)
#pragma unroll
      for (int j = 0; j < 4; ++j) {
        int row = m0 + wm * 64 + m * 16 + lhi * 4 + j;
        int col = n0 + wn * 64 + n * 16 + l15;
        C[(size_t)row * N + col] = acc[m][n][j];
      }
}

// ---------------- causal depthwise conv (K=4) + SiLU ----------------
__global__ __launch_bounds__(256) void conv_silu_kernel(const float* __restrict__ qkv,
                                                        const float* __restrict__ cw,
                                                        float* __restrict__ qkvc) {
  int idx = blockIdx.x * 256 + threadIdx.x;
  int l = idx / CONVD, c = idx - l * CONVD;
  f32x4 w = *(const f32x4*)&cw[c * 4];
  float s = qkv[idx] * w[3];
  if (l >= 1) s += qkv[idx - CONVD] * w[2];
  if (l >= 2) s += qkv[idx - 2 * CONVD] * w[1];
  if (l >= 3) s += qkv[idx - 3 * CONVD] * w[0];
  qkvc[idx] = s / (1.f + expf(-s));
}

// -------- beta/eg gates, written TRANSPOSED: egT/btT[h*1024 + l] --------
__global__ __launch_bounds__(128) void betag_kernel(const float* __restrict__ x,
                                                    const float* __restrict__ Wb,
                                                    const float* __restrict__ Wa,
                                                    const float* __restrict__ A_log,
                                                    const float* __restrict__ dt_bias,
                                                    float* __restrict__ btT,
                                                    float* __restrict__ egT) {
  int l = blockIdx.x;
  __shared__ float xs[IDIM_];
  __shared__ float redb[128], reda[128];
  for (int i = threadIdx.x; i < IDIM_; i += 128) xs[i] = x[(size_t)l * IDIM_ + i];
  __syncthreads();
  int h = threadIdx.x & 15, part = threadIdx.x >> 4;
  float sb = 0.f, sa = 0.f;
  int d0 = part * 256;
  for (int d = d0; d < d0 + 256; ++d) {
    float xv = xs[d];
    sb += xv * Wb[d * 16 + h];
    sa += xv * Wa[d * 16 + h];
  }
  redb[threadIdx.x] = sb;
  reda[threadIdx.x] = sa;
  __syncthreads();
  if (threadIdx.x < 16) {
    float b = 0.f, a = 0.f;
#pragma unroll
    for (int p = 0; p < 8; ++p) { b += redb[p * 16 + h]; a += reda[p * 16 + h]; }
    btT[h * L_SEQ + l] = 1.f / (1.f + expf(-b));
    float dtv = a + dt_bias[h];
    dtv = (dtv > 20.f) ? dtv : log1pf(expf(dtv));
    float g = -expf(A_log[h]) * dtv;
    egT[h * L_SEQ + l] = expf(g);
  }
}

// ---- l2norm q (scaled) + k, repack to [h][l][dk]; also qkT[h][l] = q.k ----
__global__ __launch_bounds__(256) void l2qk_kernel(const float* __restrict__ qkvc,
                                                   float* __restrict__ qn,
                                                   float* __restrict__ kn,
                                                   float* __restrict__ qkT) {
  int wid = blockIdx.x * 4 + (threadIdx.x >> 6);  // 16384 waves: l*16+h
  int lane = threadIdx.x & 63;
  int l = wid >> 4, h = wid & 15;
  const float* qb = qkvc + (size_t)l * CONVD + h * 128;
  const float* kb = qb + KEYD;
  f32x2 qv = *(const f32x2*)&qb[lane * 2];
  f32x2 kv = *(const f32x2*)&kb[lane * 2];
  float ssq = qv[0] * qv[0] + qv[1] * qv[1];
  float ssk = kv[0] * kv[0] + kv[1] * kv[1];
#pragma unroll
  for (int s = 1; s < 64; s <<= 1) {
    ssq += __shfl_xor(ssq, s);
    ssk += __shfl_xor(ssk, s);
  }
  float scq = 0.08838834764831845f / sqrtf(ssq + 1e-6f);  // * DK^-0.5
  float sck = 1.f / sqrtf(ssk + 1e-6f);
  qv[0] *= scq; qv[1] *= scq;
  kv[0] *= sck; kv[1] *= sck;
  size_t base = ((size_t)h * L_SEQ + l) * 128 + lane * 2;
  *(f32x2*)&qn[base] = qv;
  *(f32x2*)&kn[base] = kv;
  float qk = qv[0] * kv[0] + qv[1] * kv[1];
#pragma unroll
  for (int s = 1; s < 64; s <<= 1) qk += __shfl_xor(qk, s);
  if (lane == 0) qkT[h * L_SEQ + l] = qk;
}

// ---- transpose v slice of qkvc -> vT[c][l], c = h*128+dv ----
__global__ __launch_bounds__(256) void vtrans_kernel(const float* __restrict__ qkvc,
                                                     float* __restrict__ vT) {
  __shared__ float tile[32][33];
  int c0 = blockIdx.x * 32, l0 = blockIdx.y * 32;
  int tx = threadIdx.x & 31, ty = threadIdx.x >> 5;
#pragma unroll
  for (int j = 0; j < 4; ++j)
    tile[ty + j * 8][tx] = qkvc[(size_t)(l0 + ty + j * 8) * CONVD + 2 * KEYD + c0 + tx];
  __syncthreads();
#pragma unroll
  for (int j = 0; j < 4; ++j)
    vT[(size_t)(c0 + ty + j * 8) * L_SEQ + l0 + tx] = tile[tx][ty + j * 8];
}

// ---------------- sequential delta-rule scan v5 ----------------
// P=16 lanes/col, 4 cols/wave, 4 waves/block = 16 cols (one head, 16 dv).
// grid = 128 blocks. red16 completes the column reduce (no xor16 needed).
// All staging via global_load_lds (async); chunk-start bulk scalar loads;
// q/k ring prefetch at distance 3. No LDS-pipe ops in the recurrence chain.
__global__ __launch_bounds__(256) void scan_kernel(const float* __restrict__ qn,
                                                   const float* __restrict__ kn,
                                                   const float* __restrict__ vT,
                                                   const float* __restrict__ egT,
                                                   const float* __restrict__ btT,
                                                   const float* __restrict__ qkT,
                                                   float* __restrict__ oatt) {
  __shared__ alignas(16) float qs[2][CH][128];
  __shared__ alignas(16) float ks[2][CH][128];
  __shared__ alignas(16) float vs[2][16][CH];
  __shared__ alignas(16) float ebc[2][3][CH];

  const int tid = threadIdx.x;
  const int wave = tid >> 6, lane = tid & 63;
  const int dk_sub = lane & 15;
  const int head = blockIdx.x & 15;       // consecutive blocks -> different heads
  const int dv0 = (blockIdx.x >> 4) * 16;
  const int col_local = tid >> 4;         // 0..15
  const int dv = dv0 + col_local;

  const float* qh = qn + (size_t)head * L_SEQ * 128;
  const float* kh = kn + (size_t)head * L_SEQ * 128;

  auto stage = [&](int chunk, int buf) {
    const int l0 = chunk * CH;
    const float* qg = qh + (size_t)l0 * 128;
    const float* kg = kh + (size_t)l0 * 128;
#pragma unroll
    for (int i = 0; i < 2; ++i) {
      int seg = i * 4 + wave;             // 8 segments of 256 floats
      int off = seg * 256 + lane * 4;
      gl_lds16(qg + off, &qs[buf][0][0] + seg * 256);
      gl_lds16(kg + off, &ks[buf][0][0] + seg * 256);
    }
    {  // v: 16 cols x CH steps = 256 floats, wave w stages cols 4w..4w+3
      int idx = wave * 64 + lane;         // col = idx>>4, step = idx&15
      gl_lds4(vT + (size_t)(head * 128 + dv0 + (idx >> 4)) * L_SEQ + l0 + (idx & 15),
              &vs[buf][0][0] + wave * 64);
    }
    if (wave == 0 && lane < 48) {         // e (0-15), beta (16-31), qk (32-47)
      const float* src = (lane < 16) ? (egT + head * L_SEQ + l0 + lane)
                       : (lane < 32) ? (btT + head * L_SEQ + l0 + (lane - 16))
                                     : (qkT + head * L_SEQ + l0 + (lane - 32));
      gl_lds4(src, &ebc[buf][0][0]);      // lane l -> flat [l]
    }
  };

  stage(0, 0);
  __syncthreads();

  f32x4 Mlo = {0.f, 0.f, 0.f, 0.f}, Mhi = {0.f, 0.f, 0.f, 0.f};
  const int dkb = dk_sub * 8;

#pragma unroll 1
  for (int c = 0; c < NCH; ++c) {
    const int buf = c & 1;
    if (c + 1 < NCH) stage(c + 1, buf ^ 1);

    // chunk-start bulk loads: all per-step scalars for 16 steps into regs
    f32x4 ev[4], bv[4], cv[4], vv[4];
#pragma unroll
    for (int i = 0; i < 4; ++i) {
      ev[i] = *(const f32x4*)&ebc[buf][0][i * 4];
      bv[i] = *(const f32x4*)&ebc[buf][1][i * 4];
      cv[i] = *(const f32x4*)&ebc[buf][2][i * 4];
      vv[i] = *(const f32x4*)&vs[buf][col_local][i * 4];
    }
    // q/k ring prefetch, distance 3
    f32x4 qr[4][2], kr[4][2];
#pragma unroll
    for (int i = 0; i < 3; ++i) {
      qr[i][0] = *(const f32x4*)&qs[buf][i][dkb];
      qr[i][1] = *(const f32x4*)&qs[buf][i][dkb + 4];
      kr[i][0] = *(const f32x4*)&ks[buf][i][dkb];
      kr[i][1] = *(const f32x4*)&ks[buf][i][dkb + 4];
    }

#pragma unroll
    for (int s = 0; s < CH; ++s) {
      if (s + 3 < CH) {
        qr[(s + 3) & 3][0] = *(const f32x4*)&qs[buf][s + 3][dkb];
        qr[(s + 3) & 3][1] = *(const f32x4*)&qs[buf][s + 3][dkb + 4];
        kr[(s + 3) & 3][0] = *(const f32x4*)&ks[buf][s + 3][dkb];
        kr[(s + 3) & 3][1] = *(const f32x4*)&ks[buf][s + 3][dkb + 4];
      }
      const f32x4 q0 = qr[s & 3][0], q1 = qr[s & 3][1];
      const f32x4 k0 = kr[s & 3][0], k1 = kr[s & 3][1];
      const float e = ev[s >> 2][s & 3], b = bv[s >> 2][s & 3];
      const float qk = cv[s >> 2][s & 3], v = vv[s >> 2][s & 3];

      // dots on M_old: two independent fma chains each, depth 4+1
      float skm0 = k0[0] * Mlo[0], skm1 = k0[1] * Mlo[1];
      float sqm0 = q0[0] * Mlo[0], sqm1 = q0[1] * Mlo[1];
      skm0 = fmaf(k0[2], Mlo[2], skm0); skm1 = fmaf(k0[3], Mlo[3], skm1);
      sqm0 = fmaf(q0[2], Mlo[2], sqm0); sqm1 = fmaf(q0[3], Mlo[3], sqm1);
      skm0 = fmaf(k1[0], Mhi[0], skm0); skm1 = fmaf(k1[1], Mhi[1], skm1);
      sqm0 = fmaf(q1[0], Mhi[0], sqm0); sqm1 = fmaf(q1[1], Mhi[1], sqm1);
      skm0 = fmaf(k1[2], Mhi[2], skm0); skm1 = fmaf(k1[3], Mhi[3], skm1);
      sqm0 = fmaf(q1[2], Mhi[2], sqm0); sqm1 = fmaf(q1[3], Mhi[3], sqm1);
      // e*M_old off the skm critical path (overlaps red16)
      f32x4 emlo, emhi;
#pragma unroll
      for (int i = 0; i < 4; ++i) { emlo[i] = e * Mlo[i]; emhi[i] = e * Mhi[i]; }
      float skm = red16(skm0 + skm1);
      float sqm = red16(sqm0 + sqm1);
      float dl = (v - e * skm) * b;       // delta
      float o = fmaf(qk, dl, e * sqm);    // q . M_new
      if (dk_sub == 0)
        oatt[(size_t)((c * CH + s) * 16 + head) * 128 + dv] = o;
#pragma unroll
      for (int i = 0; i < 4; ++i) {
        Mlo[i] = fmaf(k0[i], dl, emlo[i]);
        Mhi[i] = fmaf(k1[i], dl, emhi[i]);
      }
    }
    __syncthreads();
  }
}

// ---------------- gated RMSNorm -> bf16 ----------------
__global__ __launch_bounds__(256) void grms_kernel(const float* __restrict__ oatt,
                                                   const float* __restrict__ z,
                                                   const float* __restrict__ norm_w,
                                                   u16* __restrict__ gn) {
  int wid = blockIdx.x * 4 + (threadIdx.x >> 6);
  int lane = threadIdx.x & 63;
  int l = wid >> 4, h = wid & 15;
  const float* o = oatt + (size_t)wid * 128;
  f32x2 ov = *(const f32x2*)&o[lane * 2];
  float ss = ov[0] * ov[0] + ov[1] * ov[1];
#pragma unroll
  for (int s = 1; s < 64; s <<= 1) ss += __shfl_xor(ss, s);
  float r = 1.f / sqrtf(ss * (1.f / 128.f) + 1e-6f);
  const float* zp = z + (size_t)l * VALD + h * 128;
  f32x2 zv = *(const f32x2*)&zp[lane * 2];
  u16 r0, r1;
  {
    float sil = zv[0] / (1.f + expf(-zv[0]));
    r0 = f2bf(ov[0] * r * norm_w[lane * 2] * sil);
    float sil1 = zv[1] / (1.f + expf(-zv[1]));
    r1 = f2bf(ov[1] * r * norm_w[lane * 2 + 1] * sil1);
  }
  u16* dst = gn + (size_t)l * VALD + h * 128 + lane * 2;
  dst[0] = r0; dst[1] = r1;
}

extern "C" void kernel_launch(void* const* d_in, const int* in_sizes, int n_in,
                              void* d_out, int out_size, void* d_ws, size_t ws_size,
                              hipStream_t stream) {
  const float* x      = (const float*)d_in[0];
  const float* Wqkv   = (const float*)d_in[1];
  const float* Wz     = (const float*)d_in[2];
  const float* Wb     = (const float*)d_in[3];
  const float* Wa     = (const float*)d_in[4];
  const float* conv_w = (const float*)d_in[5];
  const float* A_log  = (const float*)d_in[6];
  const float* dt_bias= (const float*)d_in[7];
  const float* norm_w = (const float*)d_in[8];
  const float* Wout   = (const float*)d_in[9];
  float* out = (float*)d_out;

  char* ws = (char*)d_ws;
  size_t off = 0;
  auto alloc = [&](size_t bytes) {
    void* p = ws + off;
    off = (off + bytes + 255) & ~(size_t)255;
    return p;
  };
  u16* xb     = (u16*)alloc((size_t)L_SEQ * IDIM_ * 2);
  u16* WqkvT  = (u16*)alloc((size_t)CONVD * IDIM_ * 2);
  u16* WzT    = (u16*)alloc((size_t)VALD * IDIM_ * 2);
  u16* WoutT  = (u16*)alloc((size_t)IDIM_ * VALD * 2);
  float* qkv  = (float*)alloc((size_t)L_SEQ * CONVD * 4);
  float* qkvc = (float*)alloc((size_t)L_SEQ * CONVD * 4);
  float* zbuf = (float*)alloc((size_t)L_SEQ * VALD * 4);
  float* btT  = (float*)alloc((size_t)L_SEQ * H_ * 4);
  float* egT  = (float*)alloc((size_t)L_SEQ * H_ * 4);
  float* qkTb = (float*)alloc((size_t)L_SEQ * H_ * 4);
  float* oatt = (float*)alloc((size_t)L_SEQ * H_ * DV_ * 4);
  u16* gn     = (u16*)alloc((size_t)L_SEQ * VALD * 2);

  // qn/kn/vT reuse the dead qkv buffer after conv (exact 24MB fit)
  float* qn = qkv;
  float* kn = qn + (size_t)H_ * L_SEQ * 128;
  float* vT = kn + (size_t)H_ * L_SEQ * 128;

  // casts / transposes
  castx_kernel<<<(L_SEQ * IDIM_) / 1024, 256, 0, stream>>>(x, xb);
  tcast_kernel<<<dim3(CONVD / 32, IDIM_ / 32), 256, 0, stream>>>(Wqkv, WqkvT, IDIM_, CONVD);
  tcast_kernel<<<dim3(VALD / 32, IDIM_ / 32), 256, 0, stream>>>(Wz, WzT, IDIM_, VALD);
  tcast_kernel<<<dim3(IDIM_ / 32, VALD / 32), 256, 0, stream>>>(Wout, WoutT, VALD, IDIM_);

  // projections
  gemm_bt_kernel<<<dim3(CONVD / 128, L_SEQ / 128), 256, 0, stream>>>(xb, WqkvT, qkv, L_SEQ, CONVD, IDIM_);
  gemm_bt_kernel<<<dim3(VALD / 128, L_SEQ / 128), 256, 0, stream>>>(xb, WzT, zbuf, L_SEQ, VALD, IDIM_);

  // conv + silu, gates
  conv_silu_kernel<<<(L_SEQ * CONVD) / 256, 256, 0, stream>>>(qkv, conv_w, qkvc);
  betag_kernel<<<L_SEQ, 128, 0, stream>>>(x, Wb, Wa, A_log, dt_bias, btT, egT);

  // repack: q/k l2norm + qk scalar -> [h][l][dk] / qkT[h][l]; v -> [h*128+dv][l]
  l2qk_kernel<<<(L_SEQ * H_) / 4, 256, 0, stream>>>(qkvc, qn, kn, qkTb);
  vtrans_kernel<<<dim3(VALD / 32, L_SEQ / 32), 256, 0, stream>>>(qkvc, vT);

  // sequential scan (128 blocks, 512 waves)
  scan_kernel<<<H_ * (DV_ / 16), 256, 0, stream>>>(qn, kn, vT, egT, btT, qkTb, oatt);

  // gated rmsnorm + final projection
  grms_kernel<<<(L_SEQ * H_) / 4, 256, 0, stream>>>(oatt, zbuf, norm_w, gn);
  gemm_bt_kernel<<<dim3(IDIM_ / 128, L_SEQ / 128), 256, 0, stream>>>(gn, WoutT, out, L_SEQ, IDIM_, VALD);
}